// Round 5
// baseline (3999.157 us; speedup 1.0000x reference)
//
#include <hip/hip_runtime.h>

typedef __bf16 bf16;
typedef __bf16 bf16x8 __attribute__((ext_vector_type(8)));
typedef __bf16 bf16x4 __attribute__((ext_vector_type(4)));
typedef float  f32x4  __attribute__((ext_vector_type(4)));

#define T_DIM 256
#define B_DIM 1024
#define HID   256
#define G4    1024
#define KIMG  784
#define KPAD  800
#define CTXD  64
#define MROWS (T_DIM*B_DIM)

__device__ __forceinline__ void gll16(const void* g, void* l) {
  __builtin_amdgcn_global_load_lds((const __attribute__((address_space(1))) void*)g,
                                   (__attribute__((address_space(3))) void*)l, 16, 0, 0);
}
__device__ __forceinline__ float sigm(float x) { return 1.f / (1.f + __expf(-x)); }
__device__ __forceinline__ float tanh_(float x) {
  x = fminf(fmaxf(x, -15.f), 15.f);
  float e = __expf(2.f * x);
  return (e - 1.f) / (e + 1.f);
}
// swizzled byte offset: row-pitch 512B, 16B chunk c XOR'd with row&7 (T2)
__device__ __forceinline__ int swz(int row, int chunk) {
  return row * 512 + (((chunk) ^ (row & 7)) << 4);
}

// ---------------- prep kernels ----------------
__global__ void k_wiT(const float* __restrict__ wi, bf16* __restrict__ wiT) {
  int n = blockIdx.x;
  for (int k = threadIdx.x; k < KPAD; k += 256) {
    float v = (k < KIMG) ? wi[(long)k * G4 + n] : 0.f;
    wiT[(long)n * KPAD + k] = (bf16)v;
  }
}
__global__ void k_whT(const float* __restrict__ wh, bf16* __restrict__ whT) {
  int n = blockIdx.x;
  int k = threadIdx.x;
  whT[n * HID + k] = (bf16)wh[k * G4 + n];
}
__global__ void k_W0T(const float* __restrict__ a0k, const float* __restrict__ cr0k,
                      bf16* __restrict__ w0t) {
  int n = blockIdx.x;
  int k = threadIdx.x;
  float v = (n < 32) ? a0k[k * 32 + n] : cr0k[k * 32 + (n - 32)];
  w0t[n * HID + k] = (bf16)v;
}
__global__ void k_dirgate(const float* __restrict__ wi, const float* __restrict__ emb_k,
                          const float* __restrict__ emb_b, const float* __restrict__ b_lstm,
                          float* __restrict__ dir_gate) {
  int d = blockIdx.x;
  for (int n = threadIdx.x; n < G4; n += 256) {
    float s = b_lstm[n];
#pragma unroll
    for (int j = 0; j < 5; ++j) s += (emb_k[d * 5 + j] + emb_b[j]) * wi[(KIMG + j) * G4 + n];
    dir_gate[d * G4 + n] = s;
  }
}
__global__ void k_ctxgate(const float* __restrict__ wi, const float* __restrict__ ctx,
                          float* __restrict__ ctx_gate) {
  int b = blockIdx.x;
  __shared__ float cs[CTXD];
  if (threadIdx.x < CTXD) cs[threadIdx.x] = ctx[b * CTXD + threadIdx.x];
  __syncthreads();
  for (int n = threadIdx.x; n < G4; n += 256) {
    float s = 0.f;
#pragma unroll 8
    for (int k = 0; k < CTXD; ++k) s += cs[k] * wi[(KIMG + 5 + k) * G4 + n];
    ctx_gate[(long)b * G4 + n] = s;
  }
}

// ---------------- conv ----------------
#define CONV_ROWS 8
__global__ void k_conv(const float* __restrict__ img, const float* __restrict__ ck,
                       const float* __restrict__ cb, bf16* __restrict__ out) {
  __shared__ float s_img[CONV_ROWS * 243];
  __shared__ float s_k[432];
  __shared__ float s_b[16];
  long r0 = (long)blockIdx.x * CONV_ROWS;
  const float* src = img + r0 * 243;
  for (int i = threadIdx.x; i < CONV_ROWS * 243; i += 256) s_img[i] = src[i];
  for (int i = threadIdx.x; i < 432; i += 256) s_k[i] = ck[i];
  if (threadIdx.x < 16) s_b[threadIdx.x] = cb[threadIdx.x];
  __syncthreads();
  for (int idx = threadIdx.x; idx < CONV_ROWS * KPAD; idx += 256) {
    int r = idx / KPAD, c = idx % KPAD;
    float v = 0.f;
    if (c < KIMG) {
      int pix = c >> 4, ch = c & 15;
      int oy = pix / 7, ox = pix % 7;
      const float* ib = s_img + r * 243 + (oy * 9 + ox) * 3;
      v = s_b[ch];
#pragma unroll
      for (int ky = 0; ky < 3; ++ky)
#pragma unroll
        for (int kx = 0; kx < 3; ++kx)
#pragma unroll
          for (int cc = 0; cc < 3; ++cc)
            v += ib[(ky * 9 + kx) * 3 + cc] * s_k[((ky * 3 + kx) * 3 + cc) * 16 + ch];
      v = fmaxf(v, 0.f);
    }
    out[r0 * KPAD + idx] = (bf16)v;
  }
}

// ---------------- big GEMM: xg = conv_out @ wi_img^T(+tables) ----------------
// Output layout: xg[(t*B + b)*1024 + unit*4 + gate]  (unit 0..255, gate 0..3)
__global__ __launch_bounds__(256, 2)
void k_gemm_xg(const bf16* __restrict__ A, const bf16* __restrict__ Bt,
               const float* __restrict__ dir_gate, const float* __restrict__ ctx_gate,
               const int* __restrict__ agent_dir, bf16* __restrict__ xg) {
  __shared__ __align__(16) bf16 As[128 * 32];
  __shared__ __align__(16) bf16 Bs[128 * 32];
  const int bid = blockIdx.x;
  const int xcd = bid & 7, local = bid >> 3;
  const long m0 = (long)(xcd * 256 + (local >> 3)) * 128;
  const int n0 = (local & 7) * 128;
  const int tid = threadIdx.x, wave = tid >> 6, lane = tid & 63;
  const int row16 = lane & 15, k8 = (lane >> 4) * 8, rowg = (lane >> 4) * 4;
  const int wr = (wave >> 1) * 64, wc = (wave & 1) * 64;

  const bf16* a_src0 = A + (m0 + tid / 4) * KPAD + (tid % 4) * 8;
  const bf16* a_src1 = A + (m0 + 64 + tid / 4) * KPAD + (tid % 4) * 8;
  const bf16* b_src0 = Bt + (long)(n0 + tid / 4) * KPAD + (tid % 4) * 8;
  const bf16* b_src1 = Bt + (long)(n0 + 64 + tid / 4) * KPAD + (tid % 4) * 8;
  bf16* asd0 = As + wave * 512;
  bf16* asd1 = As + 2048 + wave * 512;
  bf16* bsd0 = Bs + wave * 512;
  bf16* bsd1 = Bs + 2048 + wave * 512;

  f32x4 acc[4][4];
  const f32x4 zero = {0.f, 0.f, 0.f, 0.f};
#pragma unroll
  for (int i = 0; i < 4; ++i)
#pragma unroll
    for (int j = 0; j < 4; ++j) acc[i][j] = zero;

  for (int ks = 0; ks < 25; ++ks) {
    const int ko = ks * 32;
    gll16(a_src0 + ko, asd0);
    gll16(a_src1 + ko, asd1);
    gll16(b_src0 + ko, bsd0);
    gll16(b_src1 + ko, bsd1);
    __syncthreads();
    bf16x8 af[4], bfr[4];
#pragma unroll
    for (int i = 0; i < 4; ++i)
      af[i] = *(const bf16x8*)(As + (wr + 16 * i + row16) * 32 + k8);
#pragma unroll
    for (int j = 0; j < 4; ++j)
      bfr[j] = *(const bf16x8*)(Bs + (wc + 16 * j + row16) * 32 + k8);
#pragma unroll
    for (int i = 0; i < 4; ++i)
#pragma unroll
      for (int j = 0; j < 4; ++j)
        acc[i][j] = __builtin_amdgcn_mfma_f32_16x16x32_bf16(af[i], bfr[j], acc[i][j], 0, 0, 0);
    __syncthreads();
  }
#pragma unroll
  for (int i = 0; i < 4; ++i)
#pragma unroll
    for (int j = 0; j < 4; ++j)
#pragma unroll
      for (int r = 0; r < 4; ++r) {
        long row = m0 + wr + 16 * i + rowg + r;
        int colj = n0 + wc + 16 * j + row16;
        int dv = agent_dir[row];
        float base = dir_gate[dv * G4 + colj] + ctx_gate[(long)(row & 1023) * G4 + colj];
        int u = colj & 255, g = colj >> 8;
        xg[row * G4 + u * 4 + g] = (bf16)(acc[i][j][r] + base);
      }
}

// ---------------- LSTM scan ----------------
// 64 blocks x 512 threads (8 waves). Wave w owns units [32w, 32w+32).
// h double-buffered in LDS (XOR-swizzled, conflict-free); gate-i weights
// resident in LDS (swizzled); gates f,g,o streamed from L2 via 4-deep
// register buffers (distance-2, survives the barrier). ONE raw barrier/step
// (lgkmcnt only, no vmcnt drain).
__global__ __launch_bounds__(512, 1)
void k_lstm(const bf16* __restrict__ xg, const bf16* __restrict__ whT,
            const int* __restrict__ dones,
            const float* __restrict__ c0, const float* __restrict__ h0,
            bf16* __restrict__ ys, float* __restrict__ cfin, float* __restrict__ hfin) {
  __shared__ __align__(16) bf16 wc_lds[256 * 256];   // gate-i weights, 128KB, swizzled
  __shared__ __align__(16) bf16 h_lds[2][16 * 256];  // h double-buffer, swizzled
  const int tid = threadIdx.x;
  const int w = tid >> 6, lane = tid & 63;
  const int col = lane & 15;
  const int kq = lane >> 4;            // 0..3 (16B chunk sub-index)
  const int k8 = kq * 8;
  const int rowg = kq * 4;
  const int sw = col & 7;
  const int b0 = blockIdx.x * 16;
  const int ju = 32 * w + col;

  // fill resident gate-i weight cache (rows 0..255 of whT), swizzled
  for (int i = tid; i < 256 * 32; i += 512) {
    int row = i >> 5, c = i & 31;
    bf16x8 v = *(const bf16x8*)(whT + row * HID + c * 8);
    *(bf16x8*)((char*)wc_lds + swz(row, c)) = v;
  }
  // h(0) into buffer 0, swizzled
  {
    int i = tid;  // 512 threads, 512 chunks
    int m = i >> 5, c = i & 31;
    float4 f0 = *(const float4*)(h0 + (b0 + m) * HID + c * 8);
    float4 f1 = *(const float4*)(h0 + (b0 + m) * HID + c * 8 + 4);
    bf16x8 v;
    v[0] = (bf16)f0.x; v[1] = (bf16)f0.y; v[2] = (bf16)f0.z; v[3] = (bf16)f0.w;
    v[4] = (bf16)f1.x; v[5] = (bf16)f1.y; v[6] = (bf16)f1.z; v[7] = (bf16)f1.w;
    *(bf16x8*)((char*)h_lds[0] + swz(m, c)) = v;
  }
  float creg[2][4], c0reg[2][4], hnew[2][4];
  bf16 h0b[2][4];
#pragma unroll
  for (int q = 0; q < 2; ++q)
#pragma unroll
    for (int r = 0; r < 4; ++r) {
      int j = ju + 16 * q;
      float v = c0[(b0 + rowg + r) * HID + j];
      creg[q][r] = v; c0reg[q][r] = v; hnew[q][r] = 0.f;
      h0b[q][r] = (bf16)h0[(b0 + rowg + r) * HID + j];
    }
  // streamed whT row bases for gates 1..3 (gate 0 resident in LDS)
  const bf16* wb[3][2];
#pragma unroll
  for (int g = 0; g < 3; ++g)
#pragma unroll
    for (int q = 0; q < 2; ++q)
      wb[g][q] = whT + (long)((g + 1) * 256 + ju + 16 * q) * HID + k8;

  // stream prologue: chunks 0,1 into bs[0],bs[1]
  bf16x8 bs[4][3][2];
#pragma unroll
  for (int c = 0; c < 2; ++c)
#pragma unroll
    for (int g = 0; g < 3; ++g)
#pragma unroll
      for (int q = 0; q < 2; ++q)
        bs[c][g][q] = *(const bf16x8*)(wb[g][q] + c * 32);

  // xg(0), done(0)
  int4 dnA = *(const int4*)(dones + b0 + rowg);
  bf16x4 xc[2][4];
  {
    const bf16* xb = xg + (long)(b0 + rowg) * G4 + ju * 4;
#pragma unroll
    for (int q = 0; q < 2; ++q)
#pragma unroll
      for (int r = 0; r < 4; ++r)
        xc[q][r] = *(const bf16x4*)(xb + (long)r * G4 + 64 * q);
  }
  __syncthreads();

  const char* hr = (const char*)h_lds[0];
  char* hw = (char*)h_lds[1];

#pragma unroll 1
  for (int t = 0; t < T_DIM; ++t) {
    const int tn = (t + 1 < T_DIM) ? t + 1 : (T_DIM - 1);
    f32x4 acc[4][2];
    const f32x4 zero = {0.f, 0.f, 0.f, 0.f};
#pragma unroll
    for (int g = 0; g < 4; ++g) { acc[g][0] = zero; acc[g][1] = zero; }

    bf16x4 xn[2][4];
    int4 dnB;
#pragma unroll
    for (int ks = 0; ks < 8; ++ks) {
      // distance-2 stream issue; at ks=6,7 this is next step's chunks 0,1
      // (whT is t-invariant) — stays in flight across the raw barrier.
      {
        const int kf = (ks + 2) & 7, bi = (ks + 2) & 3;
#pragma unroll
        for (int g = 0; g < 3; ++g)
#pragma unroll
          for (int q = 0; q < 2; ++q)
            bs[bi][g][q] = *(const bf16x8*)(wb[g][q] + kf * 32);
      }
      if (ks == 0) {
        const bf16* xb = xg + (long)(tn * B_DIM + b0 + rowg) * G4 + ju * 4;
#pragma unroll
        for (int q = 0; q < 2; ++q)
#pragma unroll
          for (int r = 0; r < 4; ++r)
            xn[q][r] = *(const bf16x4*)(xb + (long)r * G4 + 64 * q);
        dnB = *(const int4*)(dones + (long)tn * B_DIM + b0 + rowg);
      }
      // swizzled LDS reads (conflict-free)
      const int csw = (((ks << 2) + kq) ^ sw) << 4;
      bf16x8 a = *(const bf16x8*)(hr + col * 512 + csw);
#pragma unroll
      for (int q = 0; q < 2; ++q) {
        bf16x8 b0f = *(const bf16x8*)((const char*)wc_lds + (ju + 16 * q) * 512 + csw);
        acc[0][q] = __builtin_amdgcn_mfma_f32_16x16x32_bf16(a, b0f, acc[0][q], 0, 0, 0);
      }
#pragma unroll
      for (int g = 0; g < 3; ++g)
#pragma unroll
        for (int q = 0; q < 2; ++q)
          acc[g + 1][q] = __builtin_amdgcn_mfma_f32_16x16x32_bf16(a, bs[ks & 3][g][q], acc[g + 1][q], 0, 0, 0);
    }

    int dc[4] = {dnA.x, dnA.y, dnA.z, dnA.w};
    int dx[4] = {dnB.x, dnB.y, dnB.z, dnB.w};
#pragma unroll
    for (int q = 0; q < 2; ++q) {
      const int j = ju + 16 * q;
      const int cj = j >> 3, ej = j & 7;
#pragma unroll
      for (int r = 0; r < 4; ++r) {
        float c_old = dc[r] ? c0reg[q][r] : creg[q][r];
        float gi = acc[0][q][r] + (float)xc[q][r][0];
        float gf = acc[1][q][r] + (float)xc[q][r][1];
        float gg = acc[2][q][r] + (float)xc[q][r][2];
        float go = acc[3][q][r] + (float)xc[q][r][3];
        float cn = sigm(gf) * c_old + sigm(gi) * tanh_(gg);
        float hn = sigm(go) * tanh_(cn);
        creg[q][r] = cn; hnew[q][r] = hn;
        int m = rowg + r;
        bf16 hb = (bf16)hn;
        ys[((long)t * B_DIM + b0 + m) * HID + j] = hb;
        // folded done(t+1)-reset, swizzled write into the OTHER h buffer
        *(bf16*)(hw + m * 512 + ((cj ^ (m & 7)) << 4) + ej * 2) = dx[r] ? h0b[q][r] : hb;
      }
    }
#pragma unroll
    for (int q = 0; q < 2; ++q)
#pragma unroll
      for (int r = 0; r < 4; ++r) xc[q][r] = xn[q][r];
    dnA = dnB;
    // raw barrier: LDS writes visible, global loads stay in flight
    asm volatile("s_waitcnt lgkmcnt(0)\n\ts_barrier" ::: "memory");
    { const char* tmp = hr; hr = (const char*)hw; hw = (char*)tmp; }
  }
#pragma unroll
  for (int q = 0; q < 2; ++q)
#pragma unroll
    for (int r = 0; r < 4; ++r) {
      int m = rowg + r, j = ju + 16 * q;
      cfin[(b0 + m) * HID + j] = creg[q][r];
      hfin[(b0 + m) * HID + j] = hnew[q][r];
    }
}

// ---------------- heads ----------------
__global__ __launch_bounds__(256, 2)
void k_heads1(const bf16* __restrict__ ys, const bf16* __restrict__ w0t,
              const float* __restrict__ a0b, const float* __restrict__ cr0b,
              bf16* __restrict__ h1) {
  __shared__ __align__(16) bf16 As[128 * 32];
  __shared__ __align__(16) bf16 Ws[64 * 264];
  const int tid = threadIdx.x, wave = tid >> 6, lane = tid & 63;
  const int row16 = lane & 15, k8 = (lane >> 4) * 8, rowg = (lane >> 4) * 4;
  const long m0 = (long)blockIdx.x * 128;
  for (int i = tid; i < 64 * 256; i += 256) {
    int n = i >> 8, k = i & 255;
    Ws[n * 264 + k] = w0t[i];
  }
  const bf16* a_src0 = ys + (m0 + tid / 4) * HID + (tid % 4) * 8;
  const bf16* a_src1 = ys + (m0 + 64 + tid / 4) * HID + (tid % 4) * 8;
  bf16* asd0 = As + wave * 512;
  bf16* asd1 = As + 2048 + wave * 512;
  f32x4 acc[2][4];
  const f32x4 zero = {0.f, 0.f, 0.f, 0.f};
#pragma unroll
  for (int i = 0; i < 2; ++i)
#pragma unroll
    for (int j = 0; j < 4; ++j) acc[i][j] = zero;
  for (int ks = 0; ks < 8; ++ks) {
    gll16(a_src0 + ks * 32, asd0);
    gll16(a_src1 + ks * 32, asd1);
    __syncthreads();
    bf16x8 bw[4];
#pragma unroll
    for (int j = 0; j < 4; ++j)
      bw[j] = *(const bf16x8*)(Ws + (16 * j + row16) * 264 + ks * 32 + k8);
#pragma unroll
    for (int i = 0; i < 2; ++i) {
      bf16x8 a = *(const bf16x8*)(As + (32 * wave + 16 * i + row16) * 32 + k8);
#pragma unroll
      for (int j = 0; j < 4; ++j)
        acc[i][j] = __builtin_amdgcn_mfma_f32_16x16x32_bf16(a, bw[j], acc[i][j], 0, 0, 0);
    }
    __syncthreads();
  }
#pragma unroll
  for (int i = 0; i < 2; ++i)
#pragma unroll
    for (int j = 0; j < 4; ++j)
#pragma unroll
      for (int r = 0; r < 4; ++r) {
        long row = m0 + 32 * wave + 16 * i + rowg + r;
        int n = 16 * j + row16;
        float bias = (n < 32) ? a0b[n] : cr0b[n - 32];
        h1[row * 64 + n] = (bf16)fmaxf(acc[i][j][r] + bias, 0.f);
      }
}

__global__ void k_heads2(const bf16* __restrict__ h1, const float* __restrict__ a1k,
                         const float* __restrict__ a1b, const float* __restrict__ cr1k,
                         const float* __restrict__ cr1b, float* __restrict__ logits,
                         float* __restrict__ value) {
  __shared__ float w2[32 * 8];
  int tid = threadIdx.x;
  if (tid < 224) { int k = tid / 7, c = tid % 7; w2[k * 8 + c] = a1k[tid]; }
  else if (tid < 256) { int k = tid - 224; w2[k * 8 + 7] = cr1k[k]; }
  __syncthreads();
  long r = (long)blockIdx.x * 256 + tid;
  const bf16* hp = h1 + r * 64;
  float acc7[7];
#pragma unroll
  for (int c = 0; c < 7; ++c) acc7[c] = a1b[c];
  float accv = cr1b[0];
#pragma unroll 4
  for (int k = 0; k < 32; ++k) {
    float av = (float)hp[k];
    float cv = (float)hp[32 + k];
#pragma unroll
    for (int c = 0; c < 7; ++c) acc7[c] += av * w2[k * 8 + c];
    accv += cv * w2[k * 8 + 7];
  }
#pragma unroll
  for (int c = 0; c < 7; ++c) logits[r * 7 + c] = acc7[c];
  value[r] = accv;
}

// ---------------- launch ----------------
extern "C" void kernel_launch(void* const* d_in, const int* in_sizes, int n_in,
                              void* d_out, int out_size, void* d_ws, size_t ws_size,
                              hipStream_t stream) {
  const float* image = (const float*)d_in[0];
  const int* agent_dir = (const int*)d_in[1];
  const int* dones = (const int*)d_in[2];
  const float* context = (const float*)d_in[3];
  const float* c0 = (const float*)d_in[4];
  const float* h0 = (const float*)d_in[5];
  const float* conv_k = (const float*)d_in[6];
  const float* conv_b = (const float*)d_in[7];
  const float* emb_k = (const float*)d_in[8];
  const float* emb_b = (const float*)d_in[9];
  const float* wi = (const float*)d_in[10];
  const float* wh = (const float*)d_in[11];
  const float* b_lstm = (const float*)d_in[12];
  const float* a0_k = (const float*)d_in[13];
  const float* a0_b = (const float*)d_in[14];
  const float* a1_k = (const float*)d_in[15];
  const float* a1_b = (const float*)d_in[16];
  const float* cr0_k = (const float*)d_in[17];
  const float* cr0_b = (const float*)d_in[18];
  const float* cr1_k = (const float*)d_in[19];
  const float* cr1_b = (const float*)d_in[20];

  char* ws = (char*)d_ws;
  const size_t off_conv = 0;                              // conv_out region; ys/h1 reuse
  const size_t off_xg   = 419430400ULL;
  const size_t off_wiT  = off_xg  + 536870912ULL;
  const size_t off_whT  = off_wiT + 1638400ULL;
  const size_t off_W0T  = off_whT + 524288ULL;
  const size_t off_dirg = off_W0T + 32768ULL;
  const size_t off_ctxg = off_dirg + 16384ULL;
  const size_t total    = off_ctxg + 4194304ULL;
  if (ws_size < total) return;

  bf16* conv_out = (bf16*)(ws + off_conv);
  bf16* xg       = (bf16*)(ws + off_xg);
  bf16* wiT      = (bf16*)(ws + off_wiT);
  bf16* whT      = (bf16*)(ws + off_whT);
  bf16* W0T      = (bf16*)(ws + off_W0T);
  float* dir_gate = (float*)(ws + off_dirg);
  float* ctx_gate = (float*)(ws + off_ctxg);
  bf16* ys = (bf16*)(ws + 0);               // reuses conv_out region (dead after GEMM)
  bf16* h1 = (bf16*)(ws + 134217728ULL);

  float* out_cfin = (float*)d_out;
  float* out_hfin = out_cfin + 262144;
  float* out_logits = out_cfin + 524288;
  float* out_value = out_cfin + 524288 + 1835008;

  k_wiT<<<1024, 256, 0, stream>>>(wi, wiT);
  k_whT<<<1024, 256, 0, stream>>>(wh, whT);
  k_W0T<<<64, 256, 0, stream>>>(a0_k, cr0_k, W0T);
  k_dirgate<<<4, 256, 0, stream>>>(wi, emb_k, emb_b, b_lstm, dir_gate);
  k_ctxgate<<<1024, 256, 0, stream>>>(wi, context, ctx_gate);
  k_conv<<<MROWS / CONV_ROWS, 256, 0, stream>>>(image, conv_k, conv_b, conv_out);
  k_gemm_xg<<<16384, 256, 0, stream>>>(conv_out, wiT, dir_gate, ctx_gate, agent_dir, xg);
  k_lstm<<<64, 512, 0, stream>>>(xg, whT, dones, c0, h0, ys, out_cfin, out_hfin);
  k_heads1<<<2048, 256, 0, stream>>>(ys, W0T, a0_b, cr0_b, h1);
  k_heads2<<<1024, 256, 0, stream>>>(h1, a1_k, a1_b, cr1_k, cr1_b, out_logits, out_value);
}

// Round 6
// 3228.791 us; speedup vs baseline: 1.2386x; 1.2386x over previous
//
#include <hip/hip_runtime.h>

typedef __bf16 bf16;
typedef __bf16 bf16x8 __attribute__((ext_vector_type(8)));
typedef __bf16 bf16x4 __attribute__((ext_vector_type(4)));
typedef float  f32x4  __attribute__((ext_vector_type(4)));

#define T_DIM 256
#define B_DIM 1024
#define HID   256
#define G4    1024
#define KIMG  784
#define KPAD  800
#define CTXD  64
#define MROWS (T_DIM*B_DIM)

__device__ __forceinline__ void gll16(const void* g, void* l) {
  __builtin_amdgcn_global_load_lds((const __attribute__((address_space(1))) void*)g,
                                   (__attribute__((address_space(3))) void*)l, 16, 0, 0);
}
__device__ __forceinline__ float sigm(float x) { return 1.f / (1.f + __expf(-x)); }
__device__ __forceinline__ float tanh_(float x) {
  x = fminf(fmaxf(x, -15.f), 15.f);
  float e = __expf(2.f * x);
  return (e - 1.f) / (e + 1.f);
}

// ---------------- prep kernels ----------------
__global__ void k_wiT(const float* __restrict__ wi, bf16* __restrict__ wiT) {
  int n = blockIdx.x;
  for (int k = threadIdx.x; k < KPAD; k += 256) {
    float v = (k < KIMG) ? wi[(long)k * G4 + n] : 0.f;
    wiT[(long)n * KPAD + k] = (bf16)v;
  }
}
__global__ void k_whT(const float* __restrict__ wh, bf16* __restrict__ whT) {
  int n = blockIdx.x;
  int k = threadIdx.x;
  whT[n * HID + k] = (bf16)wh[k * G4 + n];
}
__global__ void k_W0T(const float* __restrict__ a0k, const float* __restrict__ cr0k,
                      bf16* __restrict__ w0t) {
  int n = blockIdx.x;
  int k = threadIdx.x;
  float v = (n < 32) ? a0k[k * 32 + n] : cr0k[k * 32 + (n - 32)];
  w0t[n * HID + k] = (bf16)v;
}
__global__ void k_dirgate(const float* __restrict__ wi, const float* __restrict__ emb_k,
                          const float* __restrict__ emb_b, const float* __restrict__ b_lstm,
                          float* __restrict__ dir_gate) {
  int d = blockIdx.x;
  for (int n = threadIdx.x; n < G4; n += 256) {
    float s = b_lstm[n];
#pragma unroll
    for (int j = 0; j < 5; ++j) s += (emb_k[d * 5 + j] + emb_b[j]) * wi[(KIMG + j) * G4 + n];
    dir_gate[d * G4 + n] = s;
  }
}
__global__ void k_ctxgate(const float* __restrict__ wi, const float* __restrict__ ctx,
                          float* __restrict__ ctx_gate) {
  int b = blockIdx.x;
  __shared__ float cs[CTXD];
  if (threadIdx.x < CTXD) cs[threadIdx.x] = ctx[b * CTXD + threadIdx.x];
  __syncthreads();
  for (int n = threadIdx.x; n < G4; n += 256) {
    float s = 0.f;
#pragma unroll 8
    for (int k = 0; k < CTXD; ++k) s += cs[k] * wi[(KIMG + 5 + k) * G4 + n];
    ctx_gate[(long)b * G4 + n] = s;
  }
}

// ---------------- conv ----------------
#define CONV_ROWS 8
__global__ void k_conv(const float* __restrict__ img, const float* __restrict__ ck,
                       const float* __restrict__ cb, bf16* __restrict__ out) {
  __shared__ float s_img[CONV_ROWS * 243];
  __shared__ float s_k[432];
  __shared__ float s_b[16];
  long r0 = (long)blockIdx.x * CONV_ROWS;
  const float* src = img + r0 * 243;
  for (int i = threadIdx.x; i < CONV_ROWS * 243; i += 256) s_img[i] = src[i];
  for (int i = threadIdx.x; i < 432; i += 256) s_k[i] = ck[i];
  if (threadIdx.x < 16) s_b[threadIdx.x] = cb[threadIdx.x];
  __syncthreads();
  for (int idx = threadIdx.x; idx < CONV_ROWS * KPAD; idx += 256) {
    int r = idx / KPAD, c = idx % KPAD;
    float v = 0.f;
    if (c < KIMG) {
      int pix = c >> 4, ch = c & 15;
      int oy = pix / 7, ox = pix % 7;
      const float* ib = s_img + r * 243 + (oy * 9 + ox) * 3;
      v = s_b[ch];
#pragma unroll
      for (int ky = 0; ky < 3; ++ky)
#pragma unroll
        for (int kx = 0; kx < 3; ++kx)
#pragma unroll
          for (int cc = 0; cc < 3; ++cc)
            v += ib[(ky * 9 + kx) * 3 + cc] * s_k[((ky * 3 + kx) * 3 + cc) * 16 + ch];
      v = fmaxf(v, 0.f);
    }
    out[r0 * KPAD + idx] = (bf16)v;
  }
}

// ---------------- big GEMM: xg = conv_out @ wi_img^T(+tables) ----------------
// Output layout: xg[(t*B + b)*1024 + unit*4 + gate]  (unit 0..255, gate 0..3)
__global__ __launch_bounds__(256, 2)
void k_gemm_xg(const bf16* __restrict__ A, const bf16* __restrict__ Bt,
               const float* __restrict__ dir_gate, const float* __restrict__ ctx_gate,
               const int* __restrict__ agent_dir, bf16* __restrict__ xg) {
  __shared__ __align__(16) bf16 As[128 * 32];
  __shared__ __align__(16) bf16 Bs[128 * 32];
  const int bid = blockIdx.x;
  const int xcd = bid & 7, local = bid >> 3;
  const long m0 = (long)(xcd * 256 + (local >> 3)) * 128;
  const int n0 = (local & 7) * 128;
  const int tid = threadIdx.x, wave = tid >> 6, lane = tid & 63;
  const int row16 = lane & 15, k8 = (lane >> 4) * 8, rowg = (lane >> 4) * 4;
  const int wr = (wave >> 1) * 64, wc = (wave & 1) * 64;

  const bf16* a_src0 = A + (m0 + tid / 4) * KPAD + (tid % 4) * 8;
  const bf16* a_src1 = A + (m0 + 64 + tid / 4) * KPAD + (tid % 4) * 8;
  const bf16* b_src0 = Bt + (long)(n0 + tid / 4) * KPAD + (tid % 4) * 8;
  const bf16* b_src1 = Bt + (long)(n0 + 64 + tid / 4) * KPAD + (tid % 4) * 8;
  bf16* asd0 = As + wave * 512;
  bf16* asd1 = As + 2048 + wave * 512;
  bf16* bsd0 = Bs + wave * 512;
  bf16* bsd1 = Bs + 2048 + wave * 512;

  f32x4 acc[4][4];
  const f32x4 zero = {0.f, 0.f, 0.f, 0.f};
#pragma unroll
  for (int i = 0; i < 4; ++i)
#pragma unroll
    for (int j = 0; j < 4; ++j) acc[i][j] = zero;

  for (int ks = 0; ks < 25; ++ks) {
    const int ko = ks * 32;
    gll16(a_src0 + ko, asd0);
    gll16(a_src1 + ko, asd1);
    gll16(b_src0 + ko, bsd0);
    gll16(b_src1 + ko, bsd1);
    __syncthreads();
    bf16x8 af[4], bfr[4];
#pragma unroll
    for (int i = 0; i < 4; ++i)
      af[i] = *(const bf16x8*)(As + (wr + 16 * i + row16) * 32 + k8);
#pragma unroll
    for (int j = 0; j < 4; ++j)
      bfr[j] = *(const bf16x8*)(Bs + (wc + 16 * j + row16) * 32 + k8);
#pragma unroll
    for (int i = 0; i < 4; ++i)
#pragma unroll
      for (int j = 0; j < 4; ++j)
        acc[i][j] = __builtin_amdgcn_mfma_f32_16x16x32_bf16(af[i], bfr[j], acc[i][j], 0, 0, 0);
    __syncthreads();
  }
#pragma unroll
  for (int i = 0; i < 4; ++i)
#pragma unroll
    for (int j = 0; j < 4; ++j)
#pragma unroll
      for (int r = 0; r < 4; ++r) {
        long row = m0 + wr + 16 * i + rowg + r;
        int colj = n0 + wc + 16 * j + row16;
        int dv = agent_dir[row];
        float base = dir_gate[dv * G4 + colj] + ctx_gate[(long)(row & 1023) * G4 + colj];
        int u = colj & 255, g = colj >> 8;
        xg[row * G4 + u * 4 + g] = (bf16)(acc[i][j][r] + base);
      }
}

// ---------------- LSTM scan ----------------
// 64 blocks x 512 threads (8 waves). Wave w owns units [32w, 32w+32).
// h in LDS (bf16, pitch 264 = 2-way bank aliasing = free); c in registers.
// Gate-i weights resident in LDS (128KB); gate-f weights resident in
// REGISTERS (wf[2][8], 64 VGPRs/lane, loaded once, reused 256 steps);
// gates g,o streamed from L2 with distance-1 register double-buffer.
// 2 barriers/step (R4 structure).
#define WPITCH 264
__global__ __launch_bounds__(512, 1)
void k_lstm(const bf16* __restrict__ xg, const bf16* __restrict__ whT,
            const int* __restrict__ dones,
            const float* __restrict__ c0, const float* __restrict__ h0,
            bf16* __restrict__ ys, float* __restrict__ cfin, float* __restrict__ hfin) {
  __shared__ __align__(16) bf16 h_lds[16 * WPITCH];
  __shared__ __align__(16) bf16 wc_lds[256 * WPITCH];   // gate-i weights, resident
  const int tid = threadIdx.x;
  const int w = tid >> 6, lane = tid & 63;
  const int col = lane & 15;
  const int k8 = (lane >> 4) * 8;
  const int rowg = (lane >> 4) * 4;
  const int b0 = blockIdx.x * 16;
  const int ju = 32 * w + col;

  // fill resident gate-i weight cache (rows n=0..255 of whT)
  for (int i = tid; i < 256 * 32; i += 512) {
    int row = i >> 5, chunk = i & 31;
    *(bf16x8*)(wc_lds + row * WPITCH + chunk * 8) =
        *(const bf16x8*)(whT + row * HID + chunk * 8);
  }
  for (int i = tid; i < 16 * HID; i += 512) {
    int m = i >> 8, j = i & 255;
    h_lds[m * WPITCH + j] = (bf16)h0[(b0 + m) * HID + j];
  }
  // gate-f weights resident in registers: 2q x 8ks x bf16x8 = 64 VGPRs
  bf16x8 wf[2][8];
#pragma unroll
  for (int q = 0; q < 2; ++q)
#pragma unroll
    for (int ks = 0; ks < 8; ++ks)
      wf[q][ks] = *(const bf16x8*)(whT + (long)(256 + ju + 16 * q) * HID + ks * 32 + k8);

  float creg[2][4], c0reg[2][4], hnew[2][4];
  bf16 h0b[2][4];
#pragma unroll
  for (int q = 0; q < 2; ++q)
#pragma unroll
    for (int r = 0; r < 4; ++r) {
      int j = ju + 16 * q;
      float v = c0[(b0 + rowg + r) * HID + j];
      creg[q][r] = v; c0reg[q][r] = v; hnew[q][r] = 0.f;
      h0b[q][r] = (bf16)h0[(b0 + rowg + r) * HID + j];
    }
  // streamed whT row bases for gates g,o (gates 2,3)
  const bf16* wb[2][2];
#pragma unroll
  for (int g = 0; g < 2; ++g)
#pragma unroll
    for (int q = 0; q < 2; ++q)
      wb[g][q] = whT + (long)((g + 2) * 256 + ju + 16 * q) * HID + k8;

  // prologue: done(0) and xg(0)
  int4 dnA = *(const int4*)(dones + b0 + rowg);
  bf16x4 xc[2][4];
  {
    const bf16* xb = xg + (long)(b0 + rowg) * G4 + ju * 4;
#pragma unroll
    for (int q = 0; q < 2; ++q)
#pragma unroll
      for (int r = 0; r < 4; ++r)
        xc[q][r] = *(const bf16x4*)(xb + (long)r * G4 + 64 * q);
  }
  __syncthreads();

#pragma unroll 1
  for (int t = 0; t < T_DIM; ++t) {
    const int tn = (t + 1 < T_DIM) ? t + 1 : (T_DIM - 1);
    f32x4 acc[4][2];
    const f32x4 zero = {0.f, 0.f, 0.f, 0.f};
#pragma unroll
    for (int g = 0; g < 4; ++g) { acc[g][0] = zero; acc[g][1] = zero; }

    bf16x4 xn[2][4];
    int4 dnB;
    // streamed double-buffer: preload ks=0 frags for gates g,o
    bf16x8 bs_cur[2][2], bs_nxt[2][2];
#pragma unroll
    for (int g = 0; g < 2; ++g)
#pragma unroll
      for (int q = 0; q < 2; ++q) bs_cur[g][q] = *(const bf16x8*)(wb[g][q]);

#pragma unroll
    for (int ks = 0; ks < 8; ++ks) {
      // issue next ks's streamed loads first
      if (ks < 7) {
#pragma unroll
        for (int g = 0; g < 2; ++g)
#pragma unroll
          for (int q = 0; q < 2; ++q)
            bs_nxt[g][q] = *(const bf16x8*)(wb[g][q] + (ks + 1) * 32);
      }
      bf16x8 a = *(const bf16x8*)(h_lds + col * WPITCH + ks * 32 + k8);
      // gate i from resident LDS cache
#pragma unroll
      for (int q = 0; q < 2; ++q) {
        bf16x8 b0f = *(const bf16x8*)(wc_lds + (ju + 16 * q) * WPITCH + ks * 32 + k8);
        acc[0][q] = __builtin_amdgcn_mfma_f32_16x16x32_bf16(a, b0f, acc[0][q], 0, 0, 0);
      }
      // gate f from resident registers
#pragma unroll
      for (int q = 0; q < 2; ++q)
        acc[1][q] = __builtin_amdgcn_mfma_f32_16x16x32_bf16(a, wf[q][ks], acc[1][q], 0, 0, 0);
      // gates g,o from the stream
#pragma unroll
      for (int g = 0; g < 2; ++g)
#pragma unroll
        for (int q = 0; q < 2; ++q)
          acc[g + 2][q] = __builtin_amdgcn_mfma_f32_16x16x32_bf16(a, bs_cur[g][q], acc[g + 2][q], 0, 0, 0);
#pragma unroll
      for (int g = 0; g < 2; ++g)
#pragma unroll
        for (int q = 0; q < 2; ++q) bs_cur[g][q] = bs_nxt[g][q];
      if (ks == 2) {
        const bf16* xb = xg + (long)(tn * B_DIM + b0 + rowg) * G4 + ju * 4;
#pragma unroll
        for (int q = 0; q < 2; ++q)
#pragma unroll
          for (int r = 0; r < 4; ++r)
            xn[q][r] = *(const bf16x4*)(xb + (long)r * G4 + 64 * q);
        dnB = *(const int4*)(dones + (long)tn * B_DIM + b0 + rowg);
      }
    }
    __syncthreads();   // all h_lds reads complete; prefetches drained

    int dc[4] = {dnA.x, dnA.y, dnA.z, dnA.w};
    int dx[4] = {dnB.x, dnB.y, dnB.z, dnB.w};
#pragma unroll
    for (int q = 0; q < 2; ++q)
#pragma unroll
      for (int r = 0; r < 4; ++r) {
        float c_old = dc[r] ? c0reg[q][r] : creg[q][r];
        float gi = acc[0][q][r] + (float)xc[q][r][0];
        float gf = acc[1][q][r] + (float)xc[q][r][1];
        float gg = acc[2][q][r] + (float)xc[q][r][2];
        float go = acc[3][q][r] + (float)xc[q][r][3];
        float cn = sigm(gf) * c_old + sigm(gi) * tanh_(gg);
        float hn = sigm(go) * tanh_(cn);
        creg[q][r] = cn; hnew[q][r] = hn;
        int m = rowg + r, j = ju + 16 * q;
        bf16 hb = (bf16)hn;
        ys[((long)t * B_DIM + b0 + m) * HID + j] = hb;
        h_lds[m * WPITCH + j] = dx[r] ? h0b[q][r] : hb;
      }
#pragma unroll
    for (int q = 0; q < 2; ++q)
#pragma unroll
      for (int r = 0; r < 4; ++r) xc[q][r] = xn[q][r];
    dnA = dnB;
    __syncthreads();   // h writes visible for next step's GEMM
  }
#pragma unroll
  for (int q = 0; q < 2; ++q)
#pragma unroll
    for (int r = 0; r < 4; ++r) {
      int m = rowg + r, j = ju + 16 * q;
      cfin[(b0 + m) * HID + j] = creg[q][r];
      hfin[(b0 + m) * HID + j] = hnew[q][r];
    }
}

// ---------------- heads ----------------
__global__ __launch_bounds__(256, 2)
void k_heads1(const bf16* __restrict__ ys, const bf16* __restrict__ w0t,
              const float* __restrict__ a0b, const float* __restrict__ cr0b,
              bf16* __restrict__ h1) {
  __shared__ __align__(16) bf16 As[128 * 32];
  __shared__ __align__(16) bf16 Ws[64 * 264];
  const int tid = threadIdx.x, wave = tid >> 6, lane = tid & 63;
  const int row16 = lane & 15, k8 = (lane >> 4) * 8, rowg = (lane >> 4) * 4;
  const long m0 = (long)blockIdx.x * 128;
  for (int i = tid; i < 64 * 256; i += 256) {
    int n = i >> 8, k = i & 255;
    Ws[n * 264 + k] = w0t[i];
  }
  const bf16* a_src0 = ys + (m0 + tid / 4) * HID + (tid % 4) * 8;
  const bf16* a_src1 = ys + (m0 + 64 + tid / 4) * HID + (tid % 4) * 8;
  bf16* asd0 = As + wave * 512;
  bf16* asd1 = As + 2048 + wave * 512;
  f32x4 acc[2][4];
  const f32x4 zero = {0.f, 0.f, 0.f, 0.f};
#pragma unroll
  for (int i = 0; i < 2; ++i)
#pragma unroll
    for (int j = 0; j < 4; ++j) acc[i][j] = zero;
  for (int ks = 0; ks < 8; ++ks) {
    gll16(a_src0 + ks * 32, asd0);
    gll16(a_src1 + ks * 32, asd1);
    __syncthreads();
    bf16x8 bw[4];
#pragma unroll
    for (int j = 0; j < 4; ++j)
      bw[j] = *(const bf16x8*)(Ws + (16 * j + row16) * 264 + ks * 32 + k8);
#pragma unroll
    for (int i = 0; i < 2; ++i) {
      bf16x8 a = *(const bf16x8*)(As + (32 * wave + 16 * i + row16) * 32 + k8);
#pragma unroll
      for (int j = 0; j < 4; ++j)
        acc[i][j] = __builtin_amdgcn_mfma_f32_16x16x32_bf16(a, bw[j], acc[i][j], 0, 0, 0);
    }
    __syncthreads();
  }
#pragma unroll
  for (int i = 0; i < 2; ++i)
#pragma unroll
    for (int j = 0; j < 4; ++j)
#pragma unroll
      for (int r = 0; r < 4; ++r) {
        long row = m0 + 32 * wave + 16 * i + rowg + r;
        int n = 16 * j + row16;
        float bias = (n < 32) ? a0b[n] : cr0b[n - 32];
        h1[row * 64 + n] = (bf16)fmaxf(acc[i][j][r] + bias, 0.f);
      }
}

__global__ void k_heads2(const bf16* __restrict__ h1, const float* __restrict__ a1k,
                         const float* __restrict__ a1b, const float* __restrict__ cr1k,
                         const float* __restrict__ cr1b, float* __restrict__ logits,
                         float* __restrict__ value) {
  __shared__ float w2[32 * 8];
  int tid = threadIdx.x;
  if (tid < 224) { int k = tid / 7, c = tid % 7; w2[k * 8 + c] = a1k[tid]; }
  else if (tid < 256) { int k = tid - 224; w2[k * 8 + 7] = cr1k[k]; }
  __syncthreads();
  long r = (long)blockIdx.x * 256 + tid;
  const bf16* hp = h1 + r * 64;
  float acc7[7];
#pragma unroll
  for (int c = 0; c < 7; ++c) acc7[c] = a1b[c];
  float accv = cr1b[0];
#pragma unroll 4
  for (int k = 0; k < 32; ++k) {
    float av = (float)hp[k];
    float cv = (float)hp[32 + k];
#pragma unroll
    for (int c = 0; c < 7; ++c) acc7[c] += av * w2[k * 8 + c];
    accv += cv * w2[k * 8 + 7];
  }
#pragma unroll
  for (int c = 0; c < 7; ++c) logits[r * 7 + c] = acc7[c];
  value[r] = accv;
}

// ---------------- launch ----------------
extern "C" void kernel_launch(void* const* d_in, const int* in_sizes, int n_in,
                              void* d_out, int out_size, void* d_ws, size_t ws_size,
                              hipStream_t stream) {
  const float* image = (const float*)d_in[0];
  const int* agent_dir = (const int*)d_in[1];
  const int* dones = (const int*)d_in[2];
  const float* context = (const float*)d_in[3];
  const float* c0 = (const float*)d_in[4];
  const float* h0 = (const float*)d_in[5];
  const float* conv_k = (const float*)d_in[6];
  const float* conv_b = (const float*)d_in[7];
  const float* emb_k = (const float*)d_in[8];
  const float* emb_b = (const float*)d_in[9];
  const float* wi = (const float*)d_in[10];
  const float* wh = (const float*)d_in[11];
  const float* b_lstm = (const float*)d_in[12];
  const float* a0_k = (const float*)d_in[13];
  const float* a0_b = (const float*)d_in[14];
  const float* a1_k = (const float*)d_in[15];
  const float* a1_b = (const float*)d_in[16];
  const float* cr0_k = (const float*)d_in[17];
  const float* cr0_b = (const float*)d_in[18];
  const float* cr1_k = (const float*)d_in[19];
  const float* cr1_b = (const float*)d_in[20];

  char* ws = (char*)d_ws;
  const size_t off_conv = 0;                              // conv_out region; ys/h1 reuse
  const size_t off_xg   = 419430400ULL;
  const size_t off_wiT  = off_xg  + 536870912ULL;
  const size_t off_whT  = off_wiT + 1638400ULL;
  const size_t off_W0T  = off_whT + 524288ULL;
  const size_t off_dirg = off_W0T + 32768ULL;
  const size_t off_ctxg = off_dirg + 16384ULL;
  const size_t total    = off_ctxg + 4194304ULL;
  if (ws_size < total) return;

  bf16* conv_out = (bf16*)(ws + off_conv);
  bf16* xg       = (bf16*)(ws + off_xg);
  bf16* wiT      = (bf16*)(ws + off_wiT);
  bf16* whT      = (bf16*)(ws + off_whT);
  bf16* W0T      = (bf16*)(ws + off_W0T);
  float* dir_gate = (float*)(ws + off_dirg);
  float* ctx_gate = (float*)(ws + off_ctxg);
  bf16* ys = (bf16*)(ws + 0);               // reuses conv_out region (dead after GEMM)
  bf16* h1 = (bf16*)(ws + 134217728ULL);

  float* out_cfin = (float*)d_out;
  float* out_hfin = out_cfin + 262144;
  float* out_logits = out_cfin + 524288;
  float* out_value = out_cfin + 524288 + 1835008;

  k_wiT<<<1024, 256, 0, stream>>>(wi, wiT);
  k_whT<<<1024, 256, 0, stream>>>(wh, whT);
  k_W0T<<<64, 256, 0, stream>>>(a0_k, cr0_k, W0T);
  k_dirgate<<<4, 256, 0, stream>>>(wi, emb_k, emb_b, b_lstm, dir_gate);
  k_ctxgate<<<1024, 256, 0, stream>>>(wi, context, ctx_gate);
  k_conv<<<MROWS / CONV_ROWS, 256, 0, stream>>>(image, conv_k, conv_b, conv_out);
  k_gemm_xg<<<16384, 256, 0, stream>>>(conv_out, wiT, dir_gate, ctx_gate, agent_dir, xg);
  k_lstm<<<64, 512, 0, stream>>>(xg, whT, dones, c0, h0, ys, out_cfin, out_hfin);
  k_heads1<<<2048, 256, 0, stream>>>(ys, W0T, a0_b, cr0_b, h1);
  k_heads2<<<1024, 256, 0, stream>>>(h1, a1_k, a1_b, cr1_k, cr1_b, out_logits, out_value);
}